// Round 3
// baseline (1171.180 us; speedup 1.0000x reference)
//
#include <hip/hip_runtime.h>
#include <math.h>

#define NHEAD 16
#define DK 64
#define DMODEL 1024
#define BB 2
#define LQ 2048
#define LK 2048
#define MROWS (BB * LQ)  // 4096

// ---------------------------------------------------------------------------
// GEMM C = A[M,1024] @ W[1024,1024]
// MODE 0: scatter output to head layout [B, H, L, 64]
// MODE 1: add residual, write flat [M, 1024]
// Tile 128(M)x64(N), BK=16, 256 threads, 8x4 micro-tile (rows split r0/r0+64).
// A-fragment LDS reads are 16-lane broadcasts; B-fragment reads 2-way (free).
// Next k-tile global loads issued before the FMA block (latency hidden).
// ---------------------------------------------------------------------------
template <int MODE>
__global__ __launch_bounds__(256) void gemm_kernel(
    const float* __restrict__ A, const float* __restrict__ W,
    float* __restrict__ out, const float* __restrict__ res) {
  constexpr int K = DMODEL, N = DMODEL;
  __shared__ float AsT[16][132];  // [kk][row], transposed A tile, padded
  __shared__ float Bs[16][68];    // [kk][col], padded

  const int t = threadIdx.x;
  const int n0 = blockIdx.x * 64;
  const int m0 = blockIdx.y * 128;
  const int r0 = (t >> 4) << 2;   // rows r0..r0+3 and r0+64..r0+67
  const int c0 = (t & 15) << 2;   // cols c0..c0+3
  const int arow = t >> 1;        // 0..127
  const int acol = (t & 1) << 3;  // 0 or 8
  const int wrow = t >> 4;        // 0..15
  const int wcol = (t & 15) << 2; // 0..60

  float acc[2][4][4] = {};

  const float* Aptr = &A[(size_t)(m0 + arow) * K + acol];
  const float* Wptr = &W[(size_t)wrow * N + n0 + wcol];

  // prefetch k0 = 0
  float4 av0 = *(const float4*)(Aptr + 0);
  float4 av1 = *(const float4*)(Aptr + 4);
  float4 wv = *(const float4*)(Wptr);

  for (int k0 = 0; k0 < K; k0 += 16) {
    __syncthreads();  // previous iteration's LDS reads complete
    AsT[acol + 0][arow] = av0.x;
    AsT[acol + 1][arow] = av0.y;
    AsT[acol + 2][arow] = av0.z;
    AsT[acol + 3][arow] = av0.w;
    AsT[acol + 4][arow] = av1.x;
    AsT[acol + 5][arow] = av1.y;
    AsT[acol + 6][arow] = av1.z;
    AsT[acol + 7][arow] = av1.w;
    *(float4*)&Bs[wrow][wcol] = wv;
    __syncthreads();

    if (k0 + 16 < K) {  // issue next-tile loads; they overlap the FMA block
      av0 = *(const float4*)(Aptr + k0 + 16);
      av1 = *(const float4*)(Aptr + k0 + 20);
      wv = *(const float4*)(Wptr + (size_t)(k0 + 16) * N);
    }

#pragma unroll
    for (int kk = 0; kk < 16; ++kk) {
      float4 alo = *(const float4*)&AsT[kk][r0];       // broadcast across 16 lanes
      float4 ahi = *(const float4*)&AsT[kk][r0 + 64];  // broadcast
      float4 b4 = *(const float4*)&Bs[kk][c0];         // 2-way (free)
      float al[4] = {alo.x, alo.y, alo.z, alo.w};
      float ah[4] = {ahi.x, ahi.y, ahi.z, ahi.w};
      float b[4] = {b4.x, b4.y, b4.z, b4.w};
#pragma unroll
      for (int i = 0; i < 4; ++i)
#pragma unroll
        for (int j = 0; j < 4; ++j) {
          acc[0][i][j] = fmaf(al[i], b[j], acc[0][i][j]);
          acc[1][i][j] = fmaf(ah[i], b[j], acc[1][i][j]);
        }
    }
  }

  if (MODE == 0) {
    // 64-wide tile spans exactly one head.
    const int h = n0 >> 6;
#pragma unroll
    for (int half = 0; half < 2; ++half)
#pragma unroll
      for (int i = 0; i < 4; ++i) {
        const int m = m0 + half * 64 + r0 + i;
        const int b = m >> 11, l = m & (LQ - 1);
        float4 o = make_float4(acc[half][i][0], acc[half][i][1],
                               acc[half][i][2], acc[half][i][3]);
        *(float4*)&out[((size_t)(b * NHEAD + h) * LQ + l) * DK + c0] = o;
      }
  } else {
#pragma unroll
    for (int half = 0; half < 2; ++half)
#pragma unroll
      for (int i = 0; i < 4; ++i) {
        const int m = m0 + half * 64 + r0 + i;
        float4 r4 = *(const float4*)&res[(size_t)m * N + n0 + c0];
        float4 o = make_float4(acc[half][i][0] + r4.x, acc[half][i][1] + r4.y,
                               acc[half][i][2] + r4.z, acc[half][i][3] + r4.w);
        *(float4*)&out[(size_t)m * N + n0 + c0] = o;
      }
  }
}

// ---------------------------------------------------------------------------
// Flash-style attention per (b, h, 64-row q-tile).
// scores = (QK^T * mean[k] + std[k]) / 8, mask==0 -> -1e9, online softmax, @V.
// 256 threads; thread owns 4 q-rows x 4 cols. P^T reuses the K^T buffer
// (static LDS 52.2 KB -> 3 blocks/CU).
// K/V for tile t+1 are register-prefetched during tile t's compute. Current
// tile's mask/mean/std loads are issued BEFORE the K/V prefetch so the
// compiler's waitcnt at the affine step leaves the prefetch in flight.
// ---------------------------------------------------------------------------
__global__ __launch_bounds__(256) void attn_kernel(
    const float* __restrict__ Qh, const float* __restrict__ Kh,
    const float* __restrict__ Vh, const int* __restrict__ mask,
    const float* __restrict__ mean, const float* __restrict__ stdv,
    float* __restrict__ ao) {
  __shared__ float QsT[64][68];   // [d][qrow]
  __shared__ float KPsT[64][68];  // [d][kcol] for K^T, then [kcol][qrow] for P^T
  __shared__ float Vs[64][68];    // [krow][dv]

  const int t = threadIdx.x;
  const int q0 = blockIdx.x * 64;
  const int h = blockIdx.y;
  const int b = blockIdx.z;

  const float* Qb = Qh + (size_t)(b * NHEAD + h) * LQ * DK;
  const float* Kb = Kh + (size_t)(b * NHEAD + h) * LK * DK;
  const float* Vb = Vh + (size_t)(b * NHEAD + h) * LK * DK;

  const int krow = t >> 2;         // K-load row (0..63)
  const int kdc0 = (t & 3) << 2;   // K-load d base
  const int vr = t >> 4;           // V-load row base (0..15)
  const int vc = (t & 15) << 2;    // V-load col (0..60)

  {  // Q tile (transposed into LDS), once per block
#pragma unroll
    for (int p = 0; p < 4; ++p) {
      const int dc = kdc0 + p * 16;
      float4 v = *(const float4*)&Qb[(size_t)(q0 + krow) * DK + dc];
      QsT[dc + 0][krow] = v.x;
      QsT[dc + 1][krow] = v.y;
      QsT[dc + 2][krow] = v.z;
      QsT[dc + 3][krow] = v.w;
    }
  }

  // preload k-tile 0 into registers
  float4 kv0 = *(const float4*)&Kb[(size_t)krow * DK + kdc0];
  float4 kv1 = *(const float4*)&Kb[(size_t)krow * DK + kdc0 + 16];
  float4 kv2 = *(const float4*)&Kb[(size_t)krow * DK + kdc0 + 32];
  float4 kv3 = *(const float4*)&Kb[(size_t)krow * DK + kdc0 + 48];
  float4 vv0 = *(const float4*)&Vb[(size_t)(vr + 0) * DK + vc];
  float4 vv1 = *(const float4*)&Vb[(size_t)(vr + 16) * DK + vc];
  float4 vv2 = *(const float4*)&Vb[(size_t)(vr + 32) * DK + vc];
  float4 vv3 = *(const float4*)&Vb[(size_t)(vr + 48) * DK + vc];

  const int r0 = (t >> 4) << 2;  // 4 q-rows owned by this thread
  const int c0 = (t & 15) << 2;  // 4 cols owned by this thread

  float mrun[4], lrun[4];
  float O[4][4] = {};
#pragma unroll
  for (int i = 0; i < 4; ++i) {
    mrun[i] = -INFINITY;
    lrun[i] = 0.f;
  }

  for (int k0 = 0; k0 < LK; k0 += 64) {
    __syncthreads();  // previous PV reads (KPsT/Vs) done; Q write visible
    // commit the register-staged K/V tile to LDS (K transposed)
    KPsT[kdc0 + 0][krow] = kv0.x;
    KPsT[kdc0 + 1][krow] = kv0.y;
    KPsT[kdc0 + 2][krow] = kv0.z;
    KPsT[kdc0 + 3][krow] = kv0.w;
    KPsT[kdc0 + 16][krow] = kv1.x;
    KPsT[kdc0 + 17][krow] = kv1.y;
    KPsT[kdc0 + 18][krow] = kv1.z;
    KPsT[kdc0 + 19][krow] = kv1.w;
    KPsT[kdc0 + 32][krow] = kv2.x;
    KPsT[kdc0 + 33][krow] = kv2.y;
    KPsT[kdc0 + 34][krow] = kv2.z;
    KPsT[kdc0 + 35][krow] = kv2.w;
    KPsT[kdc0 + 48][krow] = kv3.x;
    KPsT[kdc0 + 49][krow] = kv3.y;
    KPsT[kdc0 + 50][krow] = kv3.z;
    KPsT[kdc0 + 51][krow] = kv3.w;
    *(float4*)&Vs[vr + 0][vc] = vv0;
    *(float4*)&Vs[vr + 16][vc] = vv1;
    *(float4*)&Vs[vr + 32][vc] = vv2;
    *(float4*)&Vs[vr + 48][vc] = vv3;
    __syncthreads();

    // ---- current tile's mask/mean/std: issued FIRST (oldest in vm queue) ----
    float4 mn = *(const float4*)&mean[(size_t)b * LK + k0 + c0];
    float4 sd = *(const float4*)&stdv[(size_t)b * LK + k0 + c0];
    int4 mk0 = *(const int4*)&mask[((size_t)b * LQ + q0 + r0 + 0) * LK + k0 + c0];
    int4 mk1 = *(const int4*)&mask[((size_t)b * LQ + q0 + r0 + 1) * LK + k0 + c0];
    int4 mk2 = *(const int4*)&mask[((size_t)b * LQ + q0 + r0 + 2) * LK + k0 + c0];
    int4 mk3 = *(const int4*)&mask[((size_t)b * LQ + q0 + r0 + 3) * LK + k0 + c0];

    // ---- next tile's K/V prefetch: stays in flight through the whole tile ----
    if (k0 + 64 < LK) {
      const float* Kn = &Kb[(size_t)(k0 + 64 + krow) * DK + kdc0];
      const float* Vn = &Vb[(size_t)(k0 + 64 + vr) * DK + vc];
      kv0 = *(const float4*)(Kn + 0);
      kv1 = *(const float4*)(Kn + 16);
      kv2 = *(const float4*)(Kn + 32);
      kv3 = *(const float4*)(Kn + 48);
      vv0 = *(const float4*)(Vn + 0 * DK);
      vv1 = *(const float4*)(Vn + 16 * DK);
      vv2 = *(const float4*)(Vn + 32 * DK);
      vv3 = *(const float4*)(Vn + 48 * DK);
    }

    // ---- scores: S[4][4] over d=64 ----
    float s[4][4] = {};
#pragma unroll 8
    for (int d = 0; d < 64; ++d) {
      float4 a4 = *(const float4*)&QsT[d][r0];
      float4 b4 = *(const float4*)&KPsT[d][c0];
      float a[4] = {a4.x, a4.y, a4.z, a4.w};
      float bb_[4] = {b4.x, b4.y, b4.z, b4.w};
#pragma unroll
      for (int i = 0; i < 4; ++i)
#pragma unroll
        for (int j = 0; j < 4; ++j) s[i][j] = fmaf(a[i], bb_[j], s[i][j]);
    }

    // ---- affine + mask (1/8 folded into per-tile mean/std) ----
    float mna[4] = {mn.x * 0.125f, mn.y * 0.125f, mn.z * 0.125f, mn.w * 0.125f};
    float sda[4] = {sd.x * 0.125f, sd.y * 0.125f, sd.z * 0.125f, sd.w * 0.125f};
    {
      int mka[4][4] = {{mk0.x, mk0.y, mk0.z, mk0.w},
                       {mk1.x, mk1.y, mk1.z, mk1.w},
                       {mk2.x, mk2.y, mk2.z, mk2.w},
                       {mk3.x, mk3.y, mk3.z, mk3.w}};
#pragma unroll
      for (int i = 0; i < 4; ++i)
#pragma unroll
        for (int j = 0; j < 4; ++j) {
          float v = fmaf(s[i][j], mna[j], sda[j]);
          s[i][j] = (mka[i][j] == 0) ? -1e9f : v;
        }
    }

    // ---- online softmax (row shared by 16 consecutive lanes) ----
#pragma unroll
    for (int i = 0; i < 4; ++i) {
      float tmax = fmaxf(fmaxf(s[i][0], s[i][1]), fmaxf(s[i][2], s[i][3]));
#pragma unroll
      for (int xm = 1; xm < 16; xm <<= 1)
        tmax = fmaxf(tmax, __shfl_xor(tmax, xm, 64));
      const float mnew = fmaxf(mrun[i], tmax);
      const float scale = __expf(mrun[i] - mnew);
      float psum = 0.f;
#pragma unroll
      for (int j = 0; j < 4; ++j) {
        s[i][j] = __expf(s[i][j] - mnew);
        psum += s[i][j];
      }
#pragma unroll
      for (int xm = 1; xm < 16; xm <<= 1) psum += __shfl_xor(psum, xm, 64);
      lrun[i] = lrun[i] * scale + psum;
      mrun[i] = mnew;
#pragma unroll
      for (int j = 0; j < 4; ++j) O[i][j] *= scale;
    }

    __syncthreads();  // all K^T reads complete before overwriting with P^T
#pragma unroll
    for (int j = 0; j < 4; ++j) {
      float4 pv = make_float4(s[0][j], s[1][j], s[2][j], s[3][j]);
      *(float4*)&KPsT[c0 + j][r0] = pv;  // P^T: [kcol][qrow]
    }
    __syncthreads();

    // ---- PV: O[i][jj] += P[r][j] * V[j][dv] ----
#pragma unroll 8
    for (int j = 0; j < 64; ++j) {
      float4 a4 = *(const float4*)&KPsT[j][r0];
      float4 b4 = *(const float4*)&Vs[j][c0];
      float a[4] = {a4.x, a4.y, a4.z, a4.w};
      float bb_[4] = {b4.x, b4.y, b4.z, b4.w};
#pragma unroll
      for (int i = 0; i < 4; ++i)
#pragma unroll
        for (int jj = 0; jj < 4; ++jj)
          O[i][jj] = fmaf(a[i], bb_[jj], O[i][jj]);
    }
  }

  // write concat-head layout [B*LQ, H*DV]
#pragma unroll
  for (int i = 0; i < 4; ++i) {
    const float inv = 1.0f / lrun[i];
    float4 o = make_float4(O[i][0] * inv, O[i][1] * inv, O[i][2] * inv,
                           O[i][3] * inv);
    *(float4*)&ao[(size_t)(b * LQ + q0 + r0 + i) * DMODEL + h * DK + c0] = o;
  }
}

// ---------------------------------------------------------------------------
// In-place row LayerNorm over 1024 elements. One block per row, 256 threads.
// ---------------------------------------------------------------------------
__global__ __launch_bounds__(256) void ln_kernel(float* __restrict__ io,
                                                 const float* __restrict__ gamma,
                                                 const float* __restrict__ beta) {
  const int row = blockIdx.x;
  const int t = threadIdx.x;
  float* base = io + (size_t)row * DMODEL;
  float4 x = *(const float4*)&base[t << 2];
  float s = x.x + x.y + x.z + x.w;
#pragma unroll
  for (int xm = 1; xm < 64; xm <<= 1) s += __shfl_xor(s, xm, 64);
  __shared__ float part[4];
  __shared__ float smu, svar;
  if ((t & 63) == 0) part[t >> 6] = s;
  __syncthreads();
  if (t == 0) smu = (part[0] + part[1] + part[2] + part[3]) * (1.0f / DMODEL);
  __syncthreads();
  const float mu = smu;
  const float d0 = x.x - mu, d1 = x.y - mu, d2 = x.z - mu, d3 = x.w - mu;
  float s2 = d0 * d0 + d1 * d1 + d2 * d2 + d3 * d3;
#pragma unroll
  for (int xm = 1; xm < 64; xm <<= 1) s2 += __shfl_xor(s2, xm, 64);
  if ((t & 63) == 0) part[t >> 6] = s2;
  __syncthreads();
  if (t == 0) svar = (part[0] + part[1] + part[2] + part[3]) * (1.0f / DMODEL);
  __syncthreads();
  const float inv = rsqrtf(svar + 1e-6f);
  float4 g = *(const float4*)&gamma[t << 2];
  float4 be = *(const float4*)&beta[t << 2];
  float4 o;
  o.x = d0 * inv * g.x + be.x;
  o.y = d1 * inv * g.y + be.y;
  o.z = d2 * inv * g.z + be.z;
  o.w = d3 * inv * g.w + be.w;
  *(float4*)&base[t << 2] = o;
}

extern "C" void kernel_launch(void* const* d_in, const int* in_sizes, int n_in,
                              void* d_out, int out_size, void* d_ws,
                              size_t ws_size, hipStream_t stream) {
  const float* q = (const float*)d_in[0];
  const float* k = (const float*)d_in[1];
  const float* v = (const float*)d_in[2];
  const int* mask = (const int*)d_in[3];
  const float* mean = (const float*)d_in[4];
  const float* stdv = (const float*)d_in[5];
  const float* w_qs = (const float*)d_in[6];
  const float* w_ks = (const float*)d_in[7];
  const float* w_vs = (const float*)d_in[8];
  const float* w_fc = (const float*)d_in[9];
  const float* gamma = (const float*)d_in[10];
  const float* beta = (const float*)d_in[11];
  float* out = (float*)d_out;

  // workspace: qh | kh | vh | attn_out  (4 x 16 MB = 64 MB)
  const size_t HSZ = (size_t)BB * NHEAD * LQ * DK;  // 4 M floats
  float* qh = (float*)d_ws;
  float* kh = qh + HSZ;
  float* vh = kh + HSZ;
  float* ao = vh + HSZ;

  dim3 blk(256);
  dim3 gg(DMODEL / 64, MROWS / 128);  // (16, 32) -> 512 blocks, 2 per CU
  gemm_kernel<0><<<gg, blk, 0, stream>>>(q, w_qs, qh, nullptr);
  gemm_kernel<0><<<gg, blk, 0, stream>>>(k, w_ks, kh, nullptr);
  gemm_kernel<0><<<gg, blk, 0, stream>>>(v, w_vs, vh, nullptr);
  attn_kernel<<<dim3(LQ / 64, NHEAD, BB), blk, 0, stream>>>(qh, kh, vh, mask,
                                                            mean, stdv, ao);
  gemm_kernel<1><<<gg, blk, 0, stream>>>(ao, w_fc, out, q);
  ln_kernel<<<MROWS, blk, 0, stream>>>(out, gamma, beta);
}

// Round 4
// 564.289 us; speedup vs baseline: 2.0755x; 2.0755x over previous
//
#include <hip/hip_runtime.h>
#include <math.h>

#define NHEAD 16
#define DK 64
#define DMODEL 1024
#define BB 2
#define LQ 2048
#define LK 2048
#define MROWS (BB * LQ)  // 4096

typedef __attribute__((ext_vector_type(8))) short short8v;   // 8 bf16 (4 VGPR)
typedef __attribute__((ext_vector_type(4))) float f32x4;
typedef __attribute__((ext_vector_type(16))) float f32x16;

__device__ __forceinline__ ushort f2bf(float x) {  // RNE fp32->bf16
  uint u = __builtin_bit_cast(uint, x);
  u += 0x7FFFu + ((u >> 16) & 1u);
  return (ushort)(u >> 16);
}
__device__ __forceinline__ float bf2f(ushort h) {
  return __builtin_bit_cast(float, ((uint)h) << 16);
}

// ---------------------------------------------------------------------------
// Split-bf16 MFMA GEMM  C = A[M,1024] @ W[1024,1024]
// Tile 128x128, BK=32, 256 thr (4 waves 2x2, wave-tile 64x64 = 4x4 frags of
// 16x16x32). A,W split to bf16 hi/lo in staging; 3 MFMA terms per frag pair.
// LDS rows 64B (32 bf16), slot-swizzle s' = s ^ ((row>>1)&3) -> bank-balanced.
// MODE 0: out[b,h,l,64]   MODE 1: out[m,1024] += residual
// ---------------------------------------------------------------------------
template <int MODE>
__global__ __launch_bounds__(256, 2) void gemm_mfma(
    const float* __restrict__ A, const float* __restrict__ W,
    float* __restrict__ out, const float* __restrict__ res) {
  __shared__ __align__(16) ushort As_hi[128 * 32], As_lo[128 * 32];
  __shared__ __align__(16) ushort Bs_hi[128 * 32], Bs_lo[128 * 32];

  const int t = threadIdx.x;
  const int ln = t & 63, wv = t >> 6;
  const int wm = wv >> 1, wn = wv & 1;
  const int n0 = blockIdx.x * 128, m0 = blockIdx.y * 128;

  const int am = t & 127, akg = t >> 7;  // A stage: row am, k-half akg (16 k)
  const int bn = t & 127, bkg = t >> 7;  // B stage: col bn, k-half bkg

  const float* Ap = A + (size_t)(m0 + am) * 1024 + akg * 16;
  const float* Wp = W + (size_t)(bkg * 16) * 1024 + n0 + bn;

  float4 apf[4];
  float wpf[16];
#pragma unroll
  for (int q = 0; q < 4; ++q) apf[q] = *(const float4*)&Ap[q * 4];
#pragma unroll
  for (int j = 0; j < 16; ++j) wpf[j] = Wp[(size_t)j * 1024];

  f32x4 acc[4][4];
#pragma unroll
  for (int i = 0; i < 4; ++i)
#pragma unroll
    for (int j = 0; j < 4; ++j)
#pragma unroll
      for (int r = 0; r < 4; ++r) acc[i][j][r] = 0.f;

  for (int k0 = 0; k0 < 1024; k0 += 32) {
    __syncthreads();
    {  // commit A (row am, slots 2*akg, 2*akg+1)
      ushort h8[16], l8[16];
#pragma unroll
      for (int q = 0; q < 4; ++q)
#pragma unroll
        for (int c = 0; c < 4; ++c) {
          float x = apf[q][c];
          ushort hb = f2bf(x);
          h8[q * 4 + c] = hb;
          l8[q * 4 + c] = f2bf(x - bf2f(hb));
        }
      const int sw = (am >> 1) & 3;
      short8v va0, va1, vb0, vb1;
#pragma unroll
      for (int i = 0; i < 8; ++i) {
        va0[i] = (short)h8[i]; va1[i] = (short)h8[8 + i];
        vb0[i] = (short)l8[i]; vb1[i] = (short)l8[8 + i];
      }
      *(short8v*)&As_hi[am * 32 + ((akg * 2) ^ sw) * 8] = va0;
      *(short8v*)&As_hi[am * 32 + ((akg * 2 + 1) ^ sw) * 8] = va1;
      *(short8v*)&As_lo[am * 32 + ((akg * 2) ^ sw) * 8] = vb0;
      *(short8v*)&As_lo[am * 32 + ((akg * 2 + 1) ^ sw) * 8] = vb1;
    }
    {  // commit B^T (row bn, k-chunk bkg*16)
      ushort h8[16], l8[16];
#pragma unroll
      for (int j = 0; j < 16; ++j) {
        float x = wpf[j];
        ushort hb = f2bf(x);
        h8[j] = hb;
        l8[j] = f2bf(x - bf2f(hb));
      }
      const int sw = (bn >> 1) & 3;
      short8v va0, va1, vb0, vb1;
#pragma unroll
      for (int i = 0; i < 8; ++i) {
        va0[i] = (short)h8[i]; va1[i] = (short)h8[8 + i];
        vb0[i] = (short)l8[i]; vb1[i] = (short)l8[8 + i];
      }
      *(short8v*)&Bs_hi[bn * 32 + ((bkg * 2) ^ sw) * 8] = va0;
      *(short8v*)&Bs_hi[bn * 32 + ((bkg * 2 + 1) ^ sw) * 8] = va1;
      *(short8v*)&Bs_lo[bn * 32 + ((bkg * 2) ^ sw) * 8] = vb0;
      *(short8v*)&Bs_lo[bn * 32 + ((bkg * 2 + 1) ^ sw) * 8] = vb1;
    }
    __syncthreads();

    if (k0 + 32 < 1024) {  // prefetch next k-tile (stays in flight over MFMA)
#pragma unroll
      for (int q = 0; q < 4; ++q) apf[q] = *(const float4*)&Ap[k0 + 32 + q * 4];
#pragma unroll
      for (int j = 0; j < 16; ++j) wpf[j] = Wp[(size_t)(k0 + 32 + j) * 1024];
    }

    short8v ah[4], al[4], bh[4], bl[4];
#pragma unroll
    for (int mf = 0; mf < 4; ++mf) {
      const int mr = wm * 64 + mf * 16 + (ln & 15);
      const int sl = (ln >> 4) ^ ((mr >> 1) & 3);
      ah[mf] = *(const short8v*)&As_hi[mr * 32 + sl * 8];
      al[mf] = *(const short8v*)&As_lo[mr * 32 + sl * 8];
    }
#pragma unroll
    for (int nf = 0; nf < 4; ++nf) {
      const int nr = wn * 64 + nf * 16 + (ln & 15);
      const int sl = (ln >> 4) ^ ((nr >> 1) & 3);
      bh[nf] = *(const short8v*)&Bs_hi[nr * 32 + sl * 8];
      bl[nf] = *(const short8v*)&Bs_lo[nr * 32 + sl * 8];
    }
#pragma unroll
    for (int mi = 0; mi < 4; ++mi)
#pragma unroll
      for (int ni = 0; ni < 4; ++ni) {
        acc[mi][ni] = __builtin_amdgcn_mfma_f32_16x16x32_bf16(
            ah[mi], bh[ni], acc[mi][ni], 0, 0, 0);
        acc[mi][ni] = __builtin_amdgcn_mfma_f32_16x16x32_bf16(
            al[mi], bh[ni], acc[mi][ni], 0, 0, 0);
        acc[mi][ni] = __builtin_amdgcn_mfma_f32_16x16x32_bf16(
            ah[mi], bl[ni], acc[mi][ni], 0, 0, 0);
      }
  }

  // epilogue: D layout col = ln&15, row = (ln>>4)*4 + r  (m89-verified)
#pragma unroll
  for (int mi = 0; mi < 4; ++mi)
#pragma unroll
    for (int ni = 0; ni < 4; ++ni) {
      const int ng = n0 + wn * 64 + ni * 16 + (ln & 15);
#pragma unroll
      for (int r = 0; r < 4; ++r) {
        const int mg = m0 + wm * 64 + mi * 16 + (ln >> 4) * 4 + r;
        if (MODE == 0) {
          const int h = ng >> 6, d = ng & 63;
          const int bb = mg >> 11, l = mg & (LQ - 1);
          out[((size_t)(bb * NHEAD + h) * LQ + l) * 64 + d] = acc[mi][ni][r];
        } else {
          out[(size_t)mg * 1024 + ng] =
              acc[mi][ni][r] + res[(size_t)mg * 1024 + ng];
        }
      }
    }
}

// ---------------------------------------------------------------------------
// MFMA flash attention, 32x32x16 bf16, swapped QK^T (S^T = K·Q^T so lane owns
// q = lane&31; softmax = 16-reg max + one shfl_xor(32)). Split-bf16: Q,K full
// split (3 terms), P split vs V split (3 terms). Per block: 4 waves x 32 q,
// KVBLK=32. K LDS swizzled (slot ^ (k&7)); V stored transposed [d][k].
// C/D: col=lane&31, row=(r&3)+8*(r>>2)+4*(lane>>5)  (m74/m101-verified)
// ---------------------------------------------------------------------------
__global__ __launch_bounds__(256, 2) void attn_mfma(
    const float* __restrict__ Qh, const float* __restrict__ Kh,
    const float* __restrict__ Vh, const int* __restrict__ mask,
    const float* __restrict__ mean, const float* __restrict__ stdv,
    float* __restrict__ ao) {
  __shared__ __align__(16) ushort Ks_hi[32 * 64], Ks_lo[32 * 64];  // [k][d swz]
  __shared__ __align__(16) ushort VT_hi[64 * 40], VT_lo[64 * 40];  // [d][k pad]
  __shared__ __align__(16) ushort P_hi[4][32 * 40], P_lo[4][32 * 40];
  __shared__ float sc_lds[4][32];

  const int t = threadIdx.x;
  const int w = t >> 6, ln = t & 63;
  const int lq = ln & 31;   // lane's q-column (and d-col in PV output)
  const int hi5 = ln >> 5;  // 0/1 half-wave

  const int q0 = blockIdx.x * 128 + w * 32;
  const int h = blockIdx.y, b = blockIdx.z;

  const float* Qb = Qh + (size_t)(b * NHEAD + h) * LK * 64;
  const float* Kb = Kh + (size_t)(b * NHEAD + h) * LK * 64;
  const float* Vb = Vh + (size_t)(b * NHEAD + h) * LK * 64;

  // ---- Q fragments in registers (B-operand: lane col q = ln&31) ----
  short8v qf_h[4], qf_l[4];
#pragma unroll
  for (int ds = 0; ds < 4; ++ds) {
    float4 x0 = *(const float4*)&Qb[(size_t)(q0 + lq) * 64 + ds * 16 + hi5 * 8];
    float4 x1 =
        *(const float4*)&Qb[(size_t)(q0 + lq) * 64 + ds * 16 + hi5 * 8 + 4];
    float xv[8] = {x0.x, x0.y, x0.z, x0.w, x1.x, x1.y, x1.z, x1.w};
#pragma unroll
    for (int j = 0; j < 8; ++j) {
      ushort hb = f2bf(xv[j]);
      qf_h[ds][j] = (short)hb;
      qf_l[ds][j] = (short)f2bf(xv[j] - bf2f(hb));
    }
  }

  // staging assignments
  const int skr = t >> 3, sds = t & 7;  // K: row skr (0..31), 8-d slot sds
  const int svd = t & 63, svk = t >> 6; // V^T: d-col svd, 8-k group svk

  float4 kpf0 = *(const float4*)&Kb[(size_t)skr * 64 + sds * 8];
  float4 kpf1 = *(const float4*)&Kb[(size_t)skr * 64 + sds * 8 + 4];
  float vpf[8];
#pragma unroll
  for (int j = 0; j < 8; ++j) vpf[j] = Vb[(size_t)(svk * 8 + j) * 64 + svd];

  f32x16 Oa[2];
#pragma unroll
  for (int dt = 0; dt < 2; ++dt)
#pragma unroll
    for (int r = 0; r < 16; ++r) Oa[dt][r] = 0.f;
  float mrun = -INFINITY, lrun = 0.f;

  for (int k0 = 0; k0 < LK; k0 += 32) {
    __syncthreads();  // prior PV reads of Ks/VT complete
    {                 // commit K tile (hi/lo), swizzled slot
      ushort h8[8], l8[8];
      float kv[8] = {kpf0.x, kpf0.y, kpf0.z, kpf0.w,
                     kpf1.x, kpf1.y, kpf1.z, kpf1.w};
#pragma unroll
      for (int j = 0; j < 8; ++j) {
        ushort hb = f2bf(kv[j]);
        h8[j] = hb;
        l8[j] = f2bf(kv[j] - bf2f(hb));
      }
      short8v vh_, vl_;
#pragma unroll
      for (int i = 0; i < 8; ++i) { vh_[i] = (short)h8[i]; vl_[i] = (short)l8[i]; }
      const int ssl = sds ^ (skr & 7);
      *(short8v*)&Ks_hi[skr * 64 + ssl * 8] = vh_;
      *(short8v*)&Ks_lo[skr * 64 + ssl * 8] = vl_;
    }
    {  // commit V^T tile
      short8v vh_, vl_;
#pragma unroll
      for (int j = 0; j < 8; ++j) {
        ushort hb = f2bf(vpf[j]);
        vh_[j] = (short)hb;
        vl_[j] = (short)f2bf(vpf[j] - bf2f(hb));
      }
      *(short8v*)&VT_hi[svd * 40 + svk * 8] = vh_;
      *(short8v*)&VT_lo[svd * 40 + svk * 8] = vl_;
    }
    __syncthreads();

    // current tile mask/mean/std (issued first -> oldest in vm queue)
    float4 mn[4], sd[4];
    int4 mk[4];
#pragma unroll
    for (int g = 0; g < 4; ++g) {
      const int kb = k0 + 8 * g + 4 * hi5;
      mn[g] = *(const float4*)&mean[(size_t)b * LK + kb];
      sd[g] = *(const float4*)&stdv[(size_t)b * LK + kb];
      mk[g] = *(const int4*)&mask[((size_t)b * LQ + q0 + lq) * LK + kb];
    }

    if (k0 + 32 < LK) {  // prefetch next K/V (in flight through the tile)
      kpf0 = *(const float4*)&Kb[(size_t)(k0 + 32 + skr) * 64 + sds * 8];
      kpf1 = *(const float4*)&Kb[(size_t)(k0 + 32 + skr) * 64 + sds * 8 + 4];
#pragma unroll
      for (int j = 0; j < 8; ++j)
        vpf[j] = Vb[(size_t)(k0 + 32 + svk * 8 + j) * 64 + svd];
    }

    // ---- S^T = K·Q^T over d (4 segs x 3 split-terms) ----
    f32x16 S;
#pragma unroll
    for (int r = 0; r < 16; ++r) S[r] = 0.f;
#pragma unroll
    for (int ds = 0; ds < 4; ++ds) {
      const int dsl = (ds * 2 + hi5) ^ (lq & 7);
      short8v kf_h = *(const short8v*)&Ks_hi[lq * 64 + dsl * 8];
      short8v kf_l = *(const short8v*)&Ks_lo[lq * 64 + dsl * 8];
      S = __builtin_amdgcn_mfma_f32_32x32x16_bf16(kf_h, qf_h[ds], S, 0, 0, 0);
      S = __builtin_amdgcn_mfma_f32_32x32x16_bf16(kf_l, qf_h[ds], S, 0, 0, 0);
      S = __builtin_amdgcn_mfma_f32_32x32x16_bf16(kf_h, qf_l[ds], S, 0, 0, 0);
    }

    // ---- affine + mask + online softmax (lane owns q = lq) ----
    float p[16];
    float tmax = -INFINITY;
#pragma unroll
    for (int r = 0; r < 16; ++r) {
      const int g = r >> 2, j = r & 3;
      float v = fmaf(S[r], ((const float*)&mn[g])[j] * 0.125f,
                     ((const float*)&sd[g])[j] * 0.125f);
      v = (((const int*)&mk[g])[j] == 0) ? -1e9f : v;
      p[r] = v;
      tmax = fmaxf(tmax, v);
    }
    tmax = fmaxf(tmax, __shfl_xor(tmax, 32, 64));
    const float mnew = fmaxf(mrun, tmax);
    const float scl = __expf(mrun - mnew);
    float psum = 0.f;
#pragma unroll
    for (int r = 0; r < 16; ++r) {
      p[r] = __expf(p[r] - mnew);
      psum += p[r];
    }
    psum += __shfl_xor(psum, 32, 64);
    lrun = lrun * scl + psum;
    mrun = mnew;

    // ---- P -> bf16 hi/lo into wave-private LDS [q][k] ----
#pragma unroll
    for (int r = 0; r < 16; r += 2) {
      const int k = (r & 3) + 8 * (r >> 2) + 4 * hi5;
      ushort h0 = f2bf(p[r]), h1 = f2bf(p[r + 1]);
      *(uint*)&P_hi[w][lq * 40 + k] = (uint)h0 | ((uint)h1 << 16);
      ushort l0 = f2bf(p[r] - bf2f(h0)), l1 = f2bf(p[r + 1] - bf2f(h1));
      *(uint*)&P_lo[w][lq * 40 + k] = (uint)l0 | ((uint)l1 << 16);
    }
    sc_lds[w][lq] = scl;  // lanes l and l+32 write same value

    // ---- rescale O by per-q scale (broadcast via LDS float4s) ----
    float4 s4[4];
#pragma unroll
    for (int g = 0; g < 4; ++g)
      s4[g] = *(const float4*)&sc_lds[w][8 * g + 4 * hi5];
#pragma unroll
    for (int dt = 0; dt < 2; ++dt)
#pragma unroll
      for (int r = 0; r < 16; ++r) Oa[dt][r] *= ((const float*)&s4[r >> 2])[r & 3];

    // ---- PV: O[q][d] += P·V  (A=P, B=V^T rows) ----
#pragma unroll
    for (int dt = 0; dt < 2; ++dt)
#pragma unroll
      for (int ki = 0; ki < 2; ++ki) {
        short8v pah = *(const short8v*)&P_hi[w][lq * 40 + ki * 16 + hi5 * 8];
        short8v pal = *(const short8v*)&P_lo[w][lq * 40 + ki * 16 + hi5 * 8];
        short8v vbh =
            *(const short8v*)&VT_hi[(dt * 32 + lq) * 40 + ki * 16 + hi5 * 8];
        short8v vbl =
            *(const short8v*)&VT_lo[(dt * 32 + lq) * 40 + ki * 16 + hi5 * 8];
        Oa[dt] = __builtin_amdgcn_mfma_f32_32x32x16_bf16(pah, vbh, Oa[dt], 0, 0, 0);
        Oa[dt] = __builtin_amdgcn_mfma_f32_32x32x16_bf16(pal, vbh, Oa[dt], 0, 0, 0);
        Oa[dt] = __builtin_amdgcn_mfma_f32_32x32x16_bf16(pah, vbl, Oa[dt], 0, 0, 0);
      }
  }

  // ---- epilogue: divide by l, write [B*LQ, H*64] (coalesced per r) ----
  sc_lds[w][lq] = 1.0f / lrun;
  float4 iv[4];
#pragma unroll
  for (int g = 0; g < 4; ++g)
    iv[g] = *(const float4*)&sc_lds[w][8 * g + 4 * hi5];
#pragma unroll
  for (int dt = 0; dt < 2; ++dt)
#pragma unroll
    for (int r = 0; r < 16; ++r) {
      const int ql = (r & 3) + 8 * (r >> 2) + 4 * hi5;
      const float v = Oa[dt][r] * ((const float*)&iv[r >> 2])[r & 3];
      ao[(size_t)(b * LQ + q0 + ql) * DMODEL + h * 64 + dt * 32 + lq] = v;
    }
}

// ---------------------------------------------------------------------------
// In-place row LayerNorm over 1024 elements. One block per row, 256 threads.
// ---------------------------------------------------------------------------
__global__ __launch_bounds__(256) void ln_kernel(float* __restrict__ io,
                                                 const float* __restrict__ gamma,
                                                 const float* __restrict__ beta) {
  const int row = blockIdx.x;
  const int t = threadIdx.x;
  float* base = io + (size_t)row * DMODEL;
  float4 x = *(const float4*)&base[t << 2];
  float s = x.x + x.y + x.z + x.w;
#pragma unroll
  for (int xm = 1; xm < 64; xm <<= 1) s += __shfl_xor(s, xm, 64);
  __shared__ float part[4];
  __shared__ float smu, svar;
  if ((t & 63) == 0) part[t >> 6] = s;
  __syncthreads();
  if (t == 0) smu = (part[0] + part[1] + part[2] + part[3]) * (1.0f / DMODEL);
  __syncthreads();
  const float mu = smu;
  const float d0 = x.x - mu, d1 = x.y - mu, d2 = x.z - mu, d3 = x.w - mu;
  float s2 = d0 * d0 + d1 * d1 + d2 * d2 + d3 * d3;
#pragma unroll
  for (int xm = 1; xm < 64; xm <<= 1) s2 += __shfl_xor(s2, xm, 64);
  if ((t & 63) == 0) part[t >> 6] = s2;
  __syncthreads();
  if (t == 0) svar = (part[0] + part[1] + part[2] + part[3]) * (1.0f / DMODEL);
  __syncthreads();
  const float inv = rsqrtf(svar + 1e-6f);
  float4 g = *(const float4*)&gamma[t << 2];
  float4 be = *(const float4*)&beta[t << 2];
  float4 o;
  o.x = d0 * inv * g.x + be.x;
  o.y = d1 * inv * g.y + be.y;
  o.z = d2 * inv * g.z + be.z;
  o.w = d3 * inv * g.w + be.w;
  *(float4*)&base[t << 2] = o;
}

extern "C" void kernel_launch(void* const* d_in, const int* in_sizes, int n_in,
                              void* d_out, int out_size, void* d_ws,
                              size_t ws_size, hipStream_t stream) {
  const float* q = (const float*)d_in[0];
  const float* k = (const float*)d_in[1];
  const float* v = (const float*)d_in[2];
  const int* mask = (const int*)d_in[3];
  const float* mean = (const float*)d_in[4];
  const float* stdv = (const float*)d_in[5];
  const float* w_qs = (const float*)d_in[6];
  const float* w_ks = (const float*)d_in[7];
  const float* w_vs = (const float*)d_in[8];
  const float* w_fc = (const float*)d_in[9];
  const float* gamma = (const float*)d_in[10];
  const float* beta = (const float*)d_in[11];
  float* out = (float*)d_out;

  // workspace: qh | kh | vh | attn_out  (4 x 16 MB = 64 MB)
  const size_t HSZ = (size_t)BB * NHEAD * LQ * DK;  // 4 M floats
  float* qh = (float*)d_ws;
  float* kh = qh + HSZ;
  float* vh = kh + HSZ;
  float* ao = vh + HSZ;

  dim3 blk(256);
  dim3 gg(DMODEL / 128, MROWS / 128);  // (8, 32) -> 256 blocks
  gemm_mfma<0><<<gg, blk, 0, stream>>>(q, w_qs, qh, nullptr);
  gemm_mfma<0><<<gg, blk, 0, stream>>>(k, w_ks, kh, nullptr);
  gemm_mfma<0><<<gg, blk, 0, stream>>>(v, w_vs, vh, nullptr);
  attn_mfma<<<dim3(LQ / 128, NHEAD, BB), blk, 0, stream>>>(qh, kh, vh, mask,
                                                           mean, stdv, ao);
  gemm_mfma<1><<<gg, blk, 0, stream>>>(ao, w_fc, out, q);
  ln_kernel<<<MROWS, blk, 0, stream>>>(out, gamma, beta);
}

// Round 5
// 547.406 us; speedup vs baseline: 2.1395x; 1.0308x over previous
//
#include <hip/hip_runtime.h>
#include <math.h>

#define NHEAD 16
#define DK 64
#define DMODEL 1024
#define BB 2
#define LQ 2048
#define LK 2048
#define MROWS (BB * LQ)  // 4096

typedef __attribute__((ext_vector_type(8))) short short8v;   // 8 bf16 (4 VGPR)
typedef __attribute__((ext_vector_type(4))) float f32x4;
typedef __attribute__((ext_vector_type(16))) float f32x16;

__device__ __forceinline__ ushort f2bf(float x) {  // RNE fp32->bf16
  uint u = __builtin_bit_cast(uint, x);
  u += 0x7FFFu + ((u >> 16) & 1u);
  return (ushort)(u >> 16);
}
__device__ __forceinline__ float bf2f(ushort h) {
  return __builtin_bit_cast(float, ((uint)h) << 16);
}

// ---------------------------------------------------------------------------
// conv_x: fp32 [n] -> hi/lo bf16 planes (same layout). Memory-bound.
// ---------------------------------------------------------------------------
__global__ __launch_bounds__(256) void conv_x(const float* __restrict__ x,
                                              ushort* __restrict__ hi,
                                              ushort* __restrict__ lo, int n4) {
  for (int i = blockIdx.x * blockDim.x + threadIdx.x; i < n4;
       i += gridDim.x * blockDim.x) {
    float4 v = ((const float4*)x)[i];
    ushort4 h, l;
    h.x = f2bf(v.x); l.x = f2bf(v.x - bf2f(h.x));
    h.y = f2bf(v.y); l.y = f2bf(v.y - bf2f(h.y));
    h.z = f2bf(v.z); l.z = f2bf(v.z - bf2f(h.z));
    h.w = f2bf(v.w); l.w = f2bf(v.w - bf2f(h.w));
    ((ushort4*)hi)[i] = h;
    ((ushort4*)lo)[i] = l;
  }
}

// ---------------------------------------------------------------------------
// conv_wT: W[1024,1024] fp32 [k][n] -> transposed hi/lo planes [n][k].
// 64x64 LDS tile per block; blockIdx.z selects one of 4 weight matrices.
// ---------------------------------------------------------------------------
__global__ __launch_bounds__(256) void conv_wT(
    const float* __restrict__ w0, const float* __restrict__ w1,
    const float* __restrict__ w2, const float* __restrict__ w3,
    ushort* __restrict__ hiB, ushort* __restrict__ loB) {
  const float* W = blockIdx.z == 0 ? w0
                   : blockIdx.z == 1 ? w1
                   : blockIdx.z == 2 ? w2 : w3;
  ushort* hi = hiB + (size_t)blockIdx.z * DMODEL * DMODEL;
  ushort* lo = loB + (size_t)blockIdx.z * DMODEL * DMODEL;
  __shared__ ushort Th[64][66], Tl[64][66];
  const int t = threadIdx.x;
  const int n0 = blockIdx.x * 64, k0 = blockIdx.y * 64;
  const int r = t >> 4, c4 = (t & 15) << 2;
#pragma unroll
  for (int p = 0; p < 4; ++p) {
    const int kr = r + p * 16;
    float4 v = *(const float4*)&W[(size_t)(k0 + kr) * DMODEL + n0 + c4];
    ushort h;
    h = f2bf(v.x); Th[c4 + 0][kr] = h; Tl[c4 + 0][kr] = f2bf(v.x - bf2f(h));
    h = f2bf(v.y); Th[c4 + 1][kr] = h; Tl[c4 + 1][kr] = f2bf(v.y - bf2f(h));
    h = f2bf(v.z); Th[c4 + 2][kr] = h; Tl[c4 + 2][kr] = f2bf(v.z - bf2f(h));
    h = f2bf(v.w); Th[c4 + 3][kr] = h; Tl[c4 + 3][kr] = f2bf(v.w - bf2f(h));
  }
  __syncthreads();
  const int n = t >> 2, g = t & 3;  // n-row, 16-k group
  uint uh[8], ul[8];
#pragma unroll
  for (int j = 0; j < 8; ++j) {
    uh[j] = *(const uint*)&Th[n][g * 16 + 2 * j];
    ul[j] = *(const uint*)&Tl[n][g * 16 + 2 * j];
  }
  const size_t ob = (size_t)(n0 + n) * DMODEL + k0 + g * 16;
  *(uint4*)&hi[ob] = make_uint4(uh[0], uh[1], uh[2], uh[3]);
  *(uint4*)&hi[ob + 8] = make_uint4(uh[4], uh[5], uh[6], uh[7]);
  *(uint4*)&lo[ob] = make_uint4(ul[0], ul[1], ul[2], ul[3]);
  *(uint4*)&lo[ob + 8] = make_uint4(ul[4], ul[5], ul[6], ul[7]);
}

// ---------------------------------------------------------------------------
// Split-bf16 MFMA GEMM from pre-split planes. A planes [M,1024]; B planes
// transposed [n][k]. Tile 128x128, BK=32, 4 waves (2x2), 4x4 frags 16x16x32.
// MODE 0: out hi/lo planes [b,h,l,64]   MODE 2: V^T planes [b,h,64,l]
// MODE 1: fp32 out [m,1024] + residual
// ---------------------------------------------------------------------------
template <int MODE>
__global__ __launch_bounds__(256, 2) void gemm_mfma(
    const ushort* __restrict__ Ah, const ushort* __restrict__ Al,
    const ushort* __restrict__ Bh, const ushort* __restrict__ Bl,
    ushort* __restrict__ Oh, ushort* __restrict__ Ol,
    float* __restrict__ outF, const float* __restrict__ res) {
  __shared__ __align__(16) ushort As_hi[128 * 32], As_lo[128 * 32];
  __shared__ __align__(16) ushort Bs_hi[128 * 32], Bs_lo[128 * 32];

  const int t = threadIdx.x;
  const int ln = t & 63, wv = t >> 6;
  const int wm = wv >> 1, wn = wv & 1;
  const int n0 = blockIdx.x * 128, m0 = blockIdx.y * 128;

  const int am = t & 127, akg = t >> 7;  // A stage: row am, 16-k half akg
  const int bn = am, bkg = akg;          // B stage: n-row bn, 16-k half

  const ushort* Aph = Ah + (size_t)(m0 + am) * 1024 + akg * 16;
  const ushort* Apl = Al + (size_t)(m0 + am) * 1024 + akg * 16;
  const ushort* Bph = Bh + (size_t)(n0 + bn) * 1024 + bkg * 16;
  const ushort* Bpl = Bl + (size_t)(n0 + bn) * 1024 + bkg * 16;

  short8v ah0 = *(const short8v*)(Aph), ah1 = *(const short8v*)(Aph + 8);
  short8v al0 = *(const short8v*)(Apl), al1 = *(const short8v*)(Apl + 8);
  short8v bh0 = *(const short8v*)(Bph), bh1 = *(const short8v*)(Bph + 8);
  short8v bl0 = *(const short8v*)(Bpl), bl1 = *(const short8v*)(Bpl + 8);

  f32x4 acc[4][4];
#pragma unroll
  for (int i = 0; i < 4; ++i)
#pragma unroll
    for (int j = 0; j < 4; ++j)
#pragma unroll
      for (int r = 0; r < 4; ++r) acc[i][j][r] = 0.f;

  const int swa = (am >> 1) & 3;
  const int s0 = (akg * 2) ^ swa, s1 = (akg * 2 + 1) ^ swa;

  for (int k0 = 0; k0 < 1024; k0 += 32) {
    __syncthreads();
    *(short8v*)&As_hi[am * 32 + s0 * 8] = ah0;
    *(short8v*)&As_hi[am * 32 + s1 * 8] = ah1;
    *(short8v*)&As_lo[am * 32 + s0 * 8] = al0;
    *(short8v*)&As_lo[am * 32 + s1 * 8] = al1;
    *(short8v*)&Bs_hi[bn * 32 + s0 * 8] = bh0;
    *(short8v*)&Bs_hi[bn * 32 + s1 * 8] = bh1;
    *(short8v*)&Bs_lo[bn * 32 + s0 * 8] = bl0;
    *(short8v*)&Bs_lo[bn * 32 + s1 * 8] = bl1;
    __syncthreads();

    if (k0 + 32 < 1024) {  // prefetch next k-tile
      ah0 = *(const short8v*)(Aph + k0 + 32);
      ah1 = *(const short8v*)(Aph + k0 + 40);
      al0 = *(const short8v*)(Apl + k0 + 32);
      al1 = *(const short8v*)(Apl + k0 + 40);
      bh0 = *(const short8v*)(Bph + k0 + 32);
      bh1 = *(const short8v*)(Bph + k0 + 40);
      bl0 = *(const short8v*)(Bpl + k0 + 32);
      bl1 = *(const short8v*)(Bpl + k0 + 40);
    }

    short8v fah[4], fal[4], fbh[4], fbl[4];
#pragma unroll
    for (int mf = 0; mf < 4; ++mf) {
      const int mr = wm * 64 + mf * 16 + (ln & 15);
      const int sl = (ln >> 4) ^ ((mr >> 1) & 3);
      fah[mf] = *(const short8v*)&As_hi[mr * 32 + sl * 8];
      fal[mf] = *(const short8v*)&As_lo[mr * 32 + sl * 8];
    }
#pragma unroll
    for (int nf = 0; nf < 4; ++nf) {
      const int nr = wn * 64 + nf * 16 + (ln & 15);
      const int sl = (ln >> 4) ^ ((nr >> 1) & 3);
      fbh[nf] = *(const short8v*)&Bs_hi[nr * 32 + sl * 8];
      fbl[nf] = *(const short8v*)&Bs_lo[nr * 32 + sl * 8];
    }
#pragma unroll
    for (int mi = 0; mi < 4; ++mi)
#pragma unroll
      for (int ni = 0; ni < 4; ++ni) {
        acc[mi][ni] = __builtin_amdgcn_mfma_f32_16x16x32_bf16(
            fah[mi], fbh[ni], acc[mi][ni], 0, 0, 0);
        acc[mi][ni] = __builtin_amdgcn_mfma_f32_16x16x32_bf16(
            fal[mi], fbh[ni], acc[mi][ni], 0, 0, 0);
        acc[mi][ni] = __builtin_amdgcn_mfma_f32_16x16x32_bf16(
            fah[mi], fbl[ni], acc[mi][ni], 0, 0, 0);
      }
  }

  // epilogue: D layout col = ln&15, row = (ln>>4)*4 + r
#pragma unroll
  for (int mi = 0; mi < 4; ++mi)
#pragma unroll
    for (int ni = 0; ni < 4; ++ni) {
      const int ng = n0 + wn * 64 + ni * 16 + (ln & 15);
#pragma unroll
      for (int r = 0; r < 4; ++r) {
        const int mg = m0 + wm * 64 + mi * 16 + (ln >> 4) * 4 + r;
        const float val = acc[mi][ni][r];
        if (MODE == 1) {
          outF[(size_t)mg * 1024 + ng] = val + res[(size_t)mg * 1024 + ng];
        } else {
          const int h = ng >> 6, d = ng & 63;
          const int bb = mg >> 11, l = mg & (LQ - 1);
          size_t idx;
          if (MODE == 0) idx = ((size_t)(bb * NHEAD + h) * LQ + l) * 64 + d;
          else           idx = ((size_t)(bb * NHEAD + h) * 64 + d) * LK + l;
          const ushort hb = f2bf(val);
          Oh[idx] = hb;
          Ol[idx] = f2bf(val - bf2f(hb));
        }
      }
    }
}

// ---------------------------------------------------------------------------
// MFMA flash attention from pre-split planes. 32x32x16, swapped QK^T.
// Q/K planes [b,h,l,64]; V planes pre-transposed [b,h,64,l]. Output ao as
// hi/lo planes [B*LQ, 1024]. Math identical to round-4 kernel.
// ---------------------------------------------------------------------------
__global__ __launch_bounds__(256, 2) void attn_mfma(
    const ushort* __restrict__ Qhh, const ushort* __restrict__ Qhl,
    const ushort* __restrict__ Khh, const ushort* __restrict__ Khl,
    const ushort* __restrict__ VTh, const ushort* __restrict__ VTl,
    const int* __restrict__ mask, const float* __restrict__ mean,
    const float* __restrict__ stdv, ushort* __restrict__ AOh,
    ushort* __restrict__ AOl) {
  __shared__ __align__(16) ushort Ks_hi[32 * 64], Ks_lo[32 * 64];  // [k][d swz]
  __shared__ __align__(16) ushort VT_hi[64 * 40], VT_lo[64 * 40];  // [d][k pad]
  __shared__ __align__(16) ushort P_hi[4][32 * 40], P_lo[4][32 * 40];
  __shared__ float sc_lds[4][32];

  const int t = threadIdx.x;
  const int w = t >> 6, ln = t & 63;
  const int lq = ln & 31;
  const int hi5 = ln >> 5;

  const int q0 = blockIdx.x * 128 + w * 32;
  const int h = blockIdx.y, b = blockIdx.z;

  const size_t hb_ = (size_t)(b * NHEAD + h);
  const ushort* Qh_ = Qhh + hb_ * LQ * 64;
  const ushort* Ql_ = Qhl + hb_ * LQ * 64;
  const ushort* Kh_ = Khh + hb_ * LK * 64;
  const ushort* Kl_ = Khl + hb_ * LK * 64;
  const ushort* Vh_ = VTh + hb_ * 64 * LK;
  const ushort* Vl_ = VTl + hb_ * 64 * LK;

  // ---- Q fragments straight from planes (B-operand; lane col q = ln&31) ----
  short8v qf_h[4], qf_l[4];
#pragma unroll
  for (int ds = 0; ds < 4; ++ds) {
    const size_t off = (size_t)(q0 + lq) * 64 + ds * 16 + hi5 * 8;
    qf_h[ds] = *(const short8v*)&Qh_[off];
    qf_l[ds] = *(const short8v*)&Ql_[off];
  }

  // staging assignments
  const int skr = t >> 3, sds = t & 7;  // K: row 0..31, 8-d slot
  const int vd = t >> 2, vg = t & 3;    // V^T: d-row 0..63, 8-k group
  const int kslot = sds ^ (skr & 7);

  short8v kp_h = *(const short8v*)&Kh_[(size_t)skr * 64 + sds * 8];
  short8v kp_l = *(const short8v*)&Kl_[(size_t)skr * 64 + sds * 8];
  short8v vp_h = *(const short8v*)&Vh_[(size_t)vd * LK + vg * 8];
  short8v vp_l = *(const short8v*)&Vl_[(size_t)vd * LK + vg * 8];

  f32x16 Oa[2];
#pragma unroll
  for (int dt = 0; dt < 2; ++dt)
#pragma unroll
    for (int r = 0; r < 16; ++r) Oa[dt][r] = 0.f;
  float mrun = -INFINITY, lrun = 0.f;

  for (int k0 = 0; k0 < LK; k0 += 32) {
    __syncthreads();  // prior PV reads of Ks/VT complete
    *(short8v*)&Ks_hi[skr * 64 + kslot * 8] = kp_h;
    *(short8v*)&Ks_lo[skr * 64 + kslot * 8] = kp_l;
    *(short8v*)&VT_hi[vd * 40 + vg * 8] = vp_h;
    *(short8v*)&VT_lo[vd * 40 + vg * 8] = vp_l;
    __syncthreads();

    // current tile mask/mean/std (issued first -> oldest in vm queue)
    float4 mn[4], sd[4];
    int4 mk[4];
#pragma unroll
    for (int g = 0; g < 4; ++g) {
      const int kb = k0 + 8 * g + 4 * hi5;
      mn[g] = *(const float4*)&mean[(size_t)b * LK + kb];
      sd[g] = *(const float4*)&stdv[(size_t)b * LK + kb];
      mk[g] = *(const int4*)&mask[((size_t)b * LQ + q0 + lq) * LK + kb];
    }

    if (k0 + 32 < LK) {  // prefetch next K/V tile
      kp_h = *(const short8v*)&Kh_[(size_t)(k0 + 32 + skr) * 64 + sds * 8];
      kp_l = *(const short8v*)&Kl_[(size_t)(k0 + 32 + skr) * 64 + sds * 8];
      vp_h = *(const short8v*)&Vh_[(size_t)vd * LK + k0 + 32 + vg * 8];
      vp_l = *(const short8v*)&Vl_[(size_t)vd * LK + k0 + 32 + vg * 8];
    }

    // ---- S^T = K·Q^T over d (4 segs x 3 split-terms) ----
    f32x16 S;
#pragma unroll
    for (int r = 0; r < 16; ++r) S[r] = 0.f;
#pragma unroll
    for (int ds = 0; ds < 4; ++ds) {
      const int dsl = (ds * 2 + hi5) ^ (lq & 7);
      short8v kf_h = *(const short8v*)&Ks_hi[lq * 64 + dsl * 8];
      short8v kf_l = *(const short8v*)&Ks_lo[lq * 64 + dsl * 8];
      S = __builtin_amdgcn_mfma_f32_32x32x16_bf16(kf_h, qf_h[ds], S, 0, 0, 0);
      S = __builtin_amdgcn_mfma_f32_32x32x16_bf16(kf_l, qf_h[ds], S, 0, 0, 0);
      S = __builtin_amdgcn_mfma_f32_32x32x16_bf16(kf_h, qf_l[ds], S, 0, 0, 0);
    }

    // ---- affine + mask + online softmax (lane owns q = lq) ----
    float p[16];
    float tmax = -INFINITY;
#pragma unroll
    for (int r = 0; r < 16; ++r) {
      const int g = r >> 2, j = r & 3;
      float v = fmaf(S[r], ((const float*)&mn[g])[j] * 0.125f,
                     ((const float*)&sd[g])[j] * 0.125f);
      v = (((const int*)&mk[g])[j] == 0) ? -1e9f : v;
      p[r] = v;
      tmax = fmaxf(tmax, v);
    }
    tmax = fmaxf(tmax, __shfl_xor(tmax, 32, 64));
    const float mnew = fmaxf(mrun, tmax);
    const float scl = __expf(mrun - mnew);
    float psum = 0.f;
#pragma unroll
    for (int r = 0; r < 16; ++r) {
      p[r] = __expf(p[r] - mnew);
      psum += p[r];
    }
    psum += __shfl_xor(psum, 32, 64);
    lrun = lrun * scl + psum;
    mrun = mnew;

    // ---- P -> bf16 hi/lo into wave-private LDS [q][k] ----
#pragma unroll
    for (int r = 0; r < 16; r += 2) {
      const int k = (r & 3) + 8 * (r >> 2) + 4 * hi5;
      ushort h0 = f2bf(p[r]), h1 = f2bf(p[r + 1]);
      *(uint*)&P_hi[w][lq * 40 + k] = (uint)h0 | ((uint)h1 << 16);
      ushort l0 = f2bf(p[r] - bf2f(h0)), l1 = f2bf(p[r + 1] - bf2f(h1));
      *(uint*)&P_lo[w][lq * 40 + k] = (uint)l0 | ((uint)l1 << 16);
    }
    sc_lds[w][lq] = scl;

    // ---- rescale O by per-q scale (broadcast via LDS float4s) ----
    float4 s4[4];
#pragma unroll
    for (int g = 0; g < 4; ++g)
      s4[g] = *(const float4*)&sc_lds[w][8 * g + 4 * hi5];
#pragma unroll
    for (int dt = 0; dt < 2; ++dt)
#pragma unroll
      for (int r = 0; r < 16; ++r) Oa[dt][r] *= ((const float*)&s4[r >> 2])[r & 3];

    // ---- PV: O[q][d] += P·V ----
#pragma unroll
    for (int dt = 0; dt < 2; ++dt)
#pragma unroll
      for (int ki = 0; ki < 2; ++ki) {
        short8v pah = *(const short8v*)&P_hi[w][lq * 40 + ki * 16 + hi5 * 8];
        short8v pal = *(const short8v*)&P_lo[w][lq * 40 + ki * 16 + hi5 * 8];
        short8v vbh =
            *(const short8v*)&VT_hi[(dt * 32 + lq) * 40 + ki * 16 + hi5 * 8];
        short8v vbl =
            *(const short8v*)&VT_lo[(dt * 32 + lq) * 40 + ki * 16 + hi5 * 8];
        Oa[dt] = __builtin_amdgcn_mfma_f32_32x32x16_bf16(pah, vbh, Oa[dt], 0, 0, 0);
        Oa[dt] = __builtin_amdgcn_mfma_f32_32x32x16_bf16(pal, vbh, Oa[dt], 0, 0, 0);
        Oa[dt] = __builtin_amdgcn_mfma_f32_32x32x16_bf16(pah, vbl, Oa[dt], 0, 0, 0);
      }
  }

  // ---- epilogue: divide by l, write ao hi/lo planes [B*LQ, 1024] ----
  sc_lds[w][lq] = 1.0f / lrun;
  float4 iv[4];
#pragma unroll
  for (int g = 0; g < 4; ++g)
    iv[g] = *(const float4*)&sc_lds[w][8 * g + 4 * hi5];
#pragma unroll
  for (int dt = 0; dt < 2; ++dt)
#pragma unroll
    for (int r = 0; r < 16; ++r) {
      const int ql = (r & 3) + 8 * (r >> 2) + 4 * hi5;
      const float v = Oa[dt][r] * ((const float*)&iv[r >> 2])[r & 3];
      const size_t idx =
          (size_t)(b * LQ + q0 + ql) * DMODEL + h * 64 + dt * 32 + lq;
      const ushort hbv = f2bf(v);
      AOh[idx] = hbv;
      AOl[idx] = f2bf(v - bf2f(hbv));
    }
}

// ---------------------------------------------------------------------------
// In-place row LayerNorm over 1024 elements. One block per row, 256 threads.
// ---------------------------------------------------------------------------
__global__ __launch_bounds__(256) void ln_kernel(float* __restrict__ io,
                                                 const float* __restrict__ gamma,
                                                 const float* __restrict__ beta) {
  const int row = blockIdx.x;
  const int t = threadIdx.x;
  float* base = io + (size_t)row * DMODEL;
  float4 x = *(const float4*)&base[t << 2];
  float s = x.x + x.y + x.z + x.w;
#pragma unroll
  for (int xm = 1; xm < 64; xm <<= 1) s += __shfl_xor(s, xm, 64);
  __shared__ float part[4];
  __shared__ float smu, svar;
  if ((t & 63) == 0) part[t >> 6] = s;
  __syncthreads();
  if (t == 0) smu = (part[0] + part[1] + part[2] + part[3]) * (1.0f / DMODEL);
  __syncthreads();
  const float mu = smu;
  const float d0 = x.x - mu, d1 = x.y - mu, d2 = x.z - mu, d3 = x.w - mu;
  float s2 = d0 * d0 + d1 * d1 + d2 * d2 + d3 * d3;
#pragma unroll
  for (int xm = 1; xm < 64; xm <<= 1) s2 += __shfl_xor(s2, xm, 64);
  if ((t & 63) == 0) part[t >> 6] = s2;
  __syncthreads();
  if (t == 0) svar = (part[0] + part[1] + part[2] + part[3]) * (1.0f / DMODEL);
  __syncthreads();
  const float inv = rsqrtf(svar + 1e-6f);
  float4 g = *(const float4*)&gamma[t << 2];
  float4 be = *(const float4*)&beta[t << 2];
  float4 o;
  o.x = d0 * inv * g.x + be.x;
  o.y = d1 * inv * g.y + be.y;
  o.z = d2 * inv * g.z + be.z;
  o.w = d3 * inv * g.w + be.w;
  *(float4*)&base[t << 2] = o;
}

extern "C" void kernel_launch(void* const* d_in, const int* in_sizes, int n_in,
                              void* d_out, int out_size, void* d_ws,
                              size_t ws_size, hipStream_t stream) {
  const float* q = (const float*)d_in[0];
  const float* k = (const float*)d_in[1];
  const float* v = (const float*)d_in[2];
  const int* mask = (const int*)d_in[3];
  const float* mean = (const float*)d_in[4];
  const float* stdv = (const float*)d_in[5];
  const float* w_qs = (const float*)d_in[6];
  const float* w_ks = (const float*)d_in[7];
  const float* w_vs = (const float*)d_in[8];
  const float* w_fc = (const float*)d_in[9];
  const float* gamma = (const float*)d_in[10];
  const float* beta = (const float*)d_in[11];
  float* out = (float*)d_out;

  // workspace (ushort planes), 80 MB total:
  // qh_h|qh_l|kh_h|kh_l|vt_h|vt_l (6x8MB) | wT_h[4]|wT_l[4] (16MB) | xs (16MB)
  const size_t PL = (size_t)MROWS * DMODEL;      // 4M elems
  const size_t WL = (size_t)DMODEL * DMODEL;     // 1M elems
  ushort* wsp = (ushort*)d_ws;
  ushort* qh_h = wsp;
  ushort* qh_l = qh_h + PL;
  ushort* kh_h = qh_l + PL;
  ushort* kh_l = kh_h + PL;
  ushort* vt_h = kh_l + PL;
  ushort* vt_l = vt_h + PL;
  ushort* wT_h = vt_l + PL;       // 4 consecutive weight planes
  ushort* wT_l = wT_h + 4 * WL;
  ushort* xs_h = wT_l + 4 * WL;
  ushort* xs_l = xs_h + PL;
  ushort* ao_h = xs_h;  // alias: xs dead after the V projection
  ushort* ao_l = xs_l;

  dim3 blk(256);
  dim3 gg(DMODEL / 128, MROWS / 128);  // (8, 32)
  const int n4 = MROWS * DMODEL / 4;

  conv_wT<<<dim3(16, 16, 4), blk, 0, stream>>>(w_qs, w_ks, w_vs, w_fc, wT_h, wT_l);

  conv_x<<<2048, blk, 0, stream>>>(q, xs_h, xs_l, n4);
  gemm_mfma<0><<<gg, blk, 0, stream>>>(xs_h, xs_l, wT_h + 0 * WL, wT_l + 0 * WL,
                                       qh_h, qh_l, nullptr, nullptr);
  conv_x<<<2048, blk, 0, stream>>>(k, xs_h, xs_l, n4);
  gemm_mfma<0><<<gg, blk, 0, stream>>>(xs_h, xs_l, wT_h + 1 * WL, wT_l + 1 * WL,
                                       kh_h, kh_l, nullptr, nullptr);
  conv_x<<<2048, blk, 0, stream>>>(v, xs_h, xs_l, n4);
  gemm_mfma<2><<<gg, blk, 0, stream>>>(xs_h, xs_l, wT_h + 2 * WL, wT_l + 2 * WL,
                                       vt_h, vt_l, nullptr, nullptr);

  attn_mfma<<<dim3(LQ / 128, NHEAD, BB), blk, 0, stream>>>(
      qh_h, qh_l, kh_h, kh_l, vt_h, vt_l, mask, mean, stdv, ao_h, ao_l);

  gemm_mfma<1><<<gg, blk, 0, stream>>>(ao_h, ao_l, wT_h + 3 * WL, wT_l + 3 * WL,
                                       nullptr, nullptr, out, q);
  ln_kernel<<<MROWS, blk, 0, stream>>>(out, gamma, beta);
}

// Round 6
// 519.452 us; speedup vs baseline: 2.2546x; 1.0538x over previous
//
#include <hip/hip_runtime.h>
#include <math.h>

#define NHEAD 16
#define DK 64
#define DMODEL 1024
#define BB 2
#define LQ 2048
#define LK 2048
#define MROWS (BB * LQ)  // 4096
#define PLANE ((size_t)MROWS * DMODEL)   // 4M elems
#define WPLANE ((size_t)DMODEL * DMODEL) // 1M elems

typedef __attribute__((ext_vector_type(8))) short short8v;   // 8 bf16 (4 VGPR)
typedef __attribute__((ext_vector_type(4))) float f32x4;
typedef __attribute__((ext_vector_type(16))) float f32x16;
typedef __attribute__((ext_vector_type(4))) uint uint4v;

__device__ __forceinline__ ushort f2bf(float x) {  // RNE fp32->bf16
  uint u = __builtin_bit_cast(uint, x);
  u += 0x7FFFu + ((u >> 16) & 1u);
  return (ushort)(u >> 16);
}
__device__ __forceinline__ float bf2f(ushort h) {
  return __builtin_bit_cast(float, ((uint)h) << 16);
}

// ---------------------------------------------------------------------------
// conv_x3: q,k,v fp32 -> hi/lo bf16 planes in one launch (z picks tensor).
// ---------------------------------------------------------------------------
__global__ __launch_bounds__(256) void conv_x3(
    const float* __restrict__ q, const float* __restrict__ k,
    const float* __restrict__ v, ushort* __restrict__ hiB,
    ushort* __restrict__ loB, int n4) {
  const int z = blockIdx.z;
  const float* x = z == 0 ? q : z == 1 ? k : v;
  ushort* hi = hiB + (size_t)z * PLANE;
  ushort* lo = loB + (size_t)z * PLANE;
  for (int i = blockIdx.x * blockDim.x + threadIdx.x; i < n4;
       i += gridDim.x * blockDim.x) {
    float4 vv = ((const float4*)x)[i];
    ushort4 h, l;
    h.x = f2bf(vv.x); l.x = f2bf(vv.x - bf2f(h.x));
    h.y = f2bf(vv.y); l.y = f2bf(vv.y - bf2f(h.y));
    h.z = f2bf(vv.z); l.z = f2bf(vv.z - bf2f(h.z));
    h.w = f2bf(vv.w); l.w = f2bf(vv.w - bf2f(h.w));
    ((ushort4*)hi)[i] = h;
    ((ushort4*)lo)[i] = l;
  }
}

// ---------------------------------------------------------------------------
// conv_wT: W[1024,1024] fp32 [k][n] -> transposed hi/lo planes [n][k].
// ---------------------------------------------------------------------------
__global__ __launch_bounds__(256) void conv_wT(
    const float* __restrict__ w0, const float* __restrict__ w1,
    const float* __restrict__ w2, const float* __restrict__ w3,
    ushort* __restrict__ hiB, ushort* __restrict__ loB) {
  const float* W = blockIdx.z == 0 ? w0
                   : blockIdx.z == 1 ? w1
                   : blockIdx.z == 2 ? w2 : w3;
  ushort* hi = hiB + (size_t)blockIdx.z * WPLANE;
  ushort* lo = loB + (size_t)blockIdx.z * WPLANE;
  __shared__ ushort Th[64][66], Tl[64][66];
  const int t = threadIdx.x;
  const int n0 = blockIdx.x * 64, k0 = blockIdx.y * 64;
  const int r = t >> 4, c4 = (t & 15) << 2;
#pragma unroll
  for (int p = 0; p < 4; ++p) {
    const int kr = r + p * 16;
    float4 v = *(const float4*)&W[(size_t)(k0 + kr) * DMODEL + n0 + c4];
    ushort h;
    h = f2bf(v.x); Th[c4 + 0][kr] = h; Tl[c4 + 0][kr] = f2bf(v.x - bf2f(h));
    h = f2bf(v.y); Th[c4 + 1][kr] = h; Tl[c4 + 1][kr] = f2bf(v.y - bf2f(h));
    h = f2bf(v.z); Th[c4 + 2][kr] = h; Tl[c4 + 2][kr] = f2bf(v.z - bf2f(h));
    h = f2bf(v.w); Th[c4 + 3][kr] = h; Tl[c4 + 3][kr] = f2bf(v.w - bf2f(h));
  }
  __syncthreads();
  const int n = t >> 2, g = t & 3;
  uint uh[8], ul[8];
#pragma unroll
  for (int j = 0; j < 8; ++j) {
    uh[j] = *(const uint*)&Th[n][g * 16 + 2 * j];
    ul[j] = *(const uint*)&Tl[n][g * 16 + 2 * j];
  }
  const size_t ob = (size_t)(n0 + n) * DMODEL + k0 + g * 16;
  *(uint4*)&hi[ob] = make_uint4(uh[0], uh[1], uh[2], uh[3]);
  *(uint4*)&hi[ob + 8] = make_uint4(uh[4], uh[5], uh[6], uh[7]);
  *(uint4*)&lo[ob] = make_uint4(ul[0], ul[1], ul[2], ul[3]);
  *(uint4*)&lo[ob + 8] = make_uint4(ul[4], ul[5], ul[6], ul[7]);
}

// ---------------------------------------------------------------------------
// Split-bf16 MFMA GEMM from pre-split planes. 128x128, BK=32, 4 waves.
// MODE 3: batched projections, z = blockIdx.z in {0,1,2}; z<2 -> head layout
//         [b,h,l,64] planes; z==2 -> V^T planes [b,h,64,l].
// MODE 1: fp32 out [m,1024] + residual (fc).
// ---------------------------------------------------------------------------
template <int MODE>
__global__ __launch_bounds__(256, 2) void gemm_mfma(
    const ushort* __restrict__ Ah, const ushort* __restrict__ Al,
    const ushort* __restrict__ Bh, const ushort* __restrict__ Bl,
    ushort* __restrict__ Oh, ushort* __restrict__ Ol,
    float* __restrict__ outF, const float* __restrict__ res) {
  __shared__ __align__(16) ushort As_hi[128 * 32], As_lo[128 * 32];
  __shared__ __align__(16) ushort Bs_hi[128 * 32], Bs_lo[128 * 32];

  const int t = threadIdx.x;
  const int ln = t & 63, wv = t >> 6;
  const int wm = wv >> 1, wn = wv & 1;
  const int n0 = blockIdx.x * 128, m0 = blockIdx.y * 128;
  const int zz = blockIdx.z;

  if (MODE == 3) {  // batched projections: offset planes by z
    Ah += (size_t)zz * PLANE;  Al += (size_t)zz * PLANE;
    Bh += (size_t)zz * WPLANE; Bl += (size_t)zz * WPLANE;
    Oh += (size_t)zz * PLANE;  Ol += (size_t)zz * PLANE;
  }

  const int am = t & 127, akg = t >> 7;  // A stage: row am, 16-k half akg
  const int bn = am, bkg = akg;          // B stage: n-row bn, 16-k half

  const ushort* Aph = Ah + (size_t)(m0 + am) * 1024 + akg * 16;
  const ushort* Apl = Al + (size_t)(m0 + am) * 1024 + akg * 16;
  const ushort* Bph = Bh + (size_t)(n0 + bn) * 1024 + bkg * 16;
  const ushort* Bpl = Bl + (size_t)(n0 + bn) * 1024 + bkg * 16;

  short8v ah0 = *(const short8v*)(Aph), ah1 = *(const short8v*)(Aph + 8);
  short8v al0 = *(const short8v*)(Apl), al1 = *(const short8v*)(Apl + 8);
  short8v bh0 = *(const short8v*)(Bph), bh1 = *(const short8v*)(Bph + 8);
  short8v bl0 = *(const short8v*)(Bpl), bl1 = *(const short8v*)(Bpl + 8);

  f32x4 acc[4][4];
#pragma unroll
  for (int i = 0; i < 4; ++i)
#pragma unroll
    for (int j = 0; j < 4; ++j)
#pragma unroll
      for (int r = 0; r < 4; ++r) acc[i][j][r] = 0.f;

  const int swa = (am >> 1) & 3;
  const int s0 = (akg * 2) ^ swa, s1 = (akg * 2 + 1) ^ swa;

  for (int k0 = 0; k0 < 1024; k0 += 32) {
    __syncthreads();
    *(short8v*)&As_hi[am * 32 + s0 * 8] = ah0;
    *(short8v*)&As_hi[am * 32 + s1 * 8] = ah1;
    *(short8v*)&As_lo[am * 32 + s0 * 8] = al0;
    *(short8v*)&As_lo[am * 32 + s1 * 8] = al1;
    *(short8v*)&Bs_hi[bn * 32 + s0 * 8] = bh0;
    *(short8v*)&Bs_hi[bn * 32 + s1 * 8] = bh1;
    *(short8v*)&Bs_lo[bn * 32 + s0 * 8] = bl0;
    *(short8v*)&Bs_lo[bn * 32 + s1 * 8] = bl1;
    __syncthreads();

    if (k0 + 32 < 1024) {  // prefetch next k-tile
      ah0 = *(const short8v*)(Aph + k0 + 32);
      ah1 = *(const short8v*)(Aph + k0 + 40);
      al0 = *(const short8v*)(Apl + k0 + 32);
      al1 = *(const short8v*)(Apl + k0 + 40);
      bh0 = *(const short8v*)(Bph + k0 + 32);
      bh1 = *(const short8v*)(Bph + k0 + 40);
      bl0 = *(const short8v*)(Bpl + k0 + 32);
      bl1 = *(const short8v*)(Bpl + k0 + 40);
    }

    short8v fah[4], fal[4], fbh[4], fbl[4];
#pragma unroll
    for (int mf = 0; mf < 4; ++mf) {
      const int mr = wm * 64 + mf * 16 + (ln & 15);
      const int sl = (ln >> 4) ^ ((mr >> 1) & 3);
      fah[mf] = *(const short8v*)&As_hi[mr * 32 + sl * 8];
      fal[mf] = *(const short8v*)&As_lo[mr * 32 + sl * 8];
    }
#pragma unroll
    for (int nf = 0; nf < 4; ++nf) {
      const int nr = wn * 64 + nf * 16 + (ln & 15);
      const int sl = (ln >> 4) ^ ((nr >> 1) & 3);
      fbh[nf] = *(const short8v*)&Bs_hi[nr * 32 + sl * 8];
      fbl[nf] = *(const short8v*)&Bs_lo[nr * 32 + sl * 8];
    }
#pragma unroll
    for (int mi = 0; mi < 4; ++mi)
#pragma unroll
      for (int ni = 0; ni < 4; ++ni) {
        acc[mi][ni] = __builtin_amdgcn_mfma_f32_16x16x32_bf16(
            fah[mi], fbh[ni], acc[mi][ni], 0, 0, 0);
        acc[mi][ni] = __builtin_amdgcn_mfma_f32_16x16x32_bf16(
            fal[mi], fbh[ni], acc[mi][ni], 0, 0, 0);
        acc[mi][ni] = __builtin_amdgcn_mfma_f32_16x16x32_bf16(
            fah[mi], fbl[ni], acc[mi][ni], 0, 0, 0);
      }
  }

  // epilogue: D layout col = ln&15, row = (ln>>4)*4 + r
#pragma unroll
  for (int mi = 0; mi < 4; ++mi)
#pragma unroll
    for (int ni = 0; ni < 4; ++ni) {
      const int ng = n0 + wn * 64 + ni * 16 + (ln & 15);
#pragma unroll
      for (int r = 0; r < 4; ++r) {
        const int mg = m0 + wm * 64 + mi * 16 + (ln >> 4) * 4 + r;
        const float val = acc[mi][ni][r];
        if (MODE == 1) {
          outF[(size_t)mg * 1024 + ng] = val + res[(size_t)mg * 1024 + ng];
        } else {
          const int h = ng >> 6, d = ng & 63;
          const int bb = mg >> 11, l = mg & (LQ - 1);
          size_t idx;
          if (zz == 2) idx = ((size_t)(bb * NHEAD + h) * 64 + d) * LK + l;
          else         idx = ((size_t)(bb * NHEAD + h) * LQ + l) * 64 + d;
          const ushort hb = f2bf(val);
          Oh[idx] = hb;
          Ol[idx] = f2bf(val - bf2f(hb));
        }
      }
    }
}

// ---------------------------------------------------------------------------
// MFMA flash attention, P kept entirely in registers.
// 32x32x16, swapped QK^T (lane owns q = lane&31). P-pack: __bf16 cvt pairs +
// v_permlane32_swap_b32 to build PV A-fragments in-register (no P LDS).
// Defer-rescale: skip O-scale when running max doesn't grow (exact skip).
// ---------------------------------------------------------------------------
__global__ __launch_bounds__(256, 2) void attn_mfma(
    const ushort* __restrict__ Qhh, const ushort* __restrict__ Qhl,
    const ushort* __restrict__ Khh, const ushort* __restrict__ Khl,
    const ushort* __restrict__ VTh, const ushort* __restrict__ VTl,
    const int* __restrict__ mask, const float* __restrict__ mean,
    const float* __restrict__ stdv, ushort* __restrict__ AOh,
    ushort* __restrict__ AOl) {
  __shared__ __align__(16) ushort Ks_hi[32 * 64], Ks_lo[32 * 64];  // [k][d swz]
  __shared__ __align__(16) ushort VT_hi[64 * 40], VT_lo[64 * 40];  // [d][k pad]
  __shared__ float sc_lds[4][32];

  const int t = threadIdx.x;
  const int w = t >> 6, ln = t & 63;
  const int lq = ln & 31;
  const int hi5 = ln >> 5;

  const int q0 = blockIdx.x * 128 + w * 32;
  const int h = blockIdx.y, b = blockIdx.z;

  const size_t hb_ = (size_t)(b * NHEAD + h);
  const ushort* Qh_ = Qhh + hb_ * LQ * 64;
  const ushort* Ql_ = Qhl + hb_ * LQ * 64;
  const ushort* Kh_ = Khh + hb_ * LK * 64;
  const ushort* Kl_ = Khl + hb_ * LK * 64;
  const ushort* Vh_ = VTh + hb_ * 64 * LK;
  const ushort* Vl_ = VTl + hb_ * 64 * LK;

  // ---- Q fragments (B-operand; lane col q = ln&31) ----
  short8v qf_h[4], qf_l[4];
#pragma unroll
  for (int ds = 0; ds < 4; ++ds) {
    const size_t off = (size_t)(q0 + lq) * 64 + ds * 16 + hi5 * 8;
    qf_h[ds] = *(const short8v*)&Qh_[off];
    qf_l[ds] = *(const short8v*)&Ql_[off];
  }

  // staging assignments
  const int skr = t >> 3, sds = t & 7;  // K: row 0..31, 8-d slot
  const int vd = t >> 2, vg = t & 3;    // V^T: d-row 0..63, 8-k group
  const int kslot = sds ^ (skr & 7);

  short8v kp_h = *(const short8v*)&Kh_[(size_t)skr * 64 + sds * 8];
  short8v kp_l = *(const short8v*)&Kl_[(size_t)skr * 64 + sds * 8];
  short8v vp_h = *(const short8v*)&Vh_[(size_t)vd * LK + vg * 8];
  short8v vp_l = *(const short8v*)&Vl_[(size_t)vd * LK + vg * 8];

  f32x16 Oa[2];
#pragma unroll
  for (int dt = 0; dt < 2; ++dt)
#pragma unroll
    for (int r = 0; r < 16; ++r) Oa[dt][r] = 0.f;
  float mrun = -INFINITY, lrun = 0.f;

  for (int k0 = 0; k0 < LK; k0 += 32) {
    __syncthreads();  // prior PV reads of Ks/VT complete
    *(short8v*)&Ks_hi[skr * 64 + kslot * 8] = kp_h;
    *(short8v*)&Ks_lo[skr * 64 + kslot * 8] = kp_l;
    *(short8v*)&VT_hi[vd * 40 + vg * 8] = vp_h;
    *(short8v*)&VT_lo[vd * 40 + vg * 8] = vp_l;
    __syncthreads();

    // current tile mask/mean/std (issued first -> oldest in vm queue)
    float4 mn[4], sd[4];
    int4 mk[4];
#pragma unroll
    for (int g = 0; g < 4; ++g) {
      const int kb = k0 + 8 * g + 4 * hi5;
      mn[g] = *(const float4*)&mean[(size_t)b * LK + kb];
      sd[g] = *(const float4*)&stdv[(size_t)b * LK + kb];
      mk[g] = *(const int4*)&mask[((size_t)b * LQ + q0 + lq) * LK + kb];
    }

    if (k0 + 32 < LK) {  // prefetch next K/V tile
      kp_h = *(const short8v*)&Kh_[(size_t)(k0 + 32 + skr) * 64 + sds * 8];
      kp_l = *(const short8v*)&Kl_[(size_t)(k0 + 32 + skr) * 64 + sds * 8];
      vp_h = *(const short8v*)&Vh_[(size_t)vd * LK + k0 + 32 + vg * 8];
      vp_l = *(const short8v*)&Vl_[(size_t)vd * LK + k0 + 32 + vg * 8];
    }

    // ---- S^T = K·Q^T over d (4 segs x 3 split-terms) ----
    f32x16 S;
#pragma unroll
    for (int r = 0; r < 16; ++r) S[r] = 0.f;
#pragma unroll
    for (int ds = 0; ds < 4; ++ds) {
      const int dsl = (ds * 2 + hi5) ^ (lq & 7);
      short8v kf_h = *(const short8v*)&Ks_hi[lq * 64 + dsl * 8];
      short8v kf_l = *(const short8v*)&Ks_lo[lq * 64 + dsl * 8];
      S = __builtin_amdgcn_mfma_f32_32x32x16_bf16(kf_h, qf_h[ds], S, 0, 0, 0);
      S = __builtin_amdgcn_mfma_f32_32x32x16_bf16(kf_l, qf_h[ds], S, 0, 0, 0);
      S = __builtin_amdgcn_mfma_f32_32x32x16_bf16(kf_h, qf_l[ds], S, 0, 0, 0);
    }

    // ---- affine + mask + online softmax (lane owns q = lq) ----
    float p[16];
    float tmax = -INFINITY;
#pragma unroll
    for (int r = 0; r < 16; ++r) {
      const int g = r >> 2, j = r & 3;
      float v = fmaf(S[r], ((const float*)&mn[g])[j] * 0.125f,
                     ((const float*)&sd[g])[j] * 0.125f);
      v = (((const int*)&mk[g])[j] == 0) ? -1e9f : v;
      p[r] = v;
      tmax = fmaxf(tmax, v);
    }
    tmax = fmaxf(tmax, __shfl_xor(tmax, 32, 64));
    const bool need = __any(tmax > mrun);
    const float mnew = need ? fmaxf(mrun, tmax) : mrun;
    float psum = 0.f;
#pragma unroll
    for (int r = 0; r < 16; ++r) {
      p[r] = __expf(p[r] - mnew);
      psum += p[r];
    }
    psum += __shfl_xor(psum, 32, 64);
    if (need) {
      const float scl = __expf(mrun - mnew);
      lrun = lrun * scl + psum;
      mrun = mnew;
      sc_lds[w][lq] = scl;  // lanes lq and lq+32 write the same value
      float4 s4[4];
#pragma unroll
      for (int g = 0; g < 4; ++g)
        s4[g] = *(const float4*)&sc_lds[w][8 * g + 4 * hi5];
#pragma unroll
      for (int dt = 0; dt < 2; ++dt)
#pragma unroll
        for (int r = 0; r < 16; ++r)
          Oa[dt][r] *= ((const float*)&s4[r >> 2])[r & 3];
    } else {
      lrun += psum;  // scl == 1 exactly
    }

    // ---- P -> bf16 hi/lo PV A-fragments, all in registers ----
    // lane(lq,hi5) holds k = (r&3)+8*(r>>2)+4*hi5; pack pairs then
    // permlane32_swap (x.hi <-> y.lo) assembles A-frag uints directly.
    uint ch[8], cl[8];
#pragma unroll
    for (int j = 0; j < 8; ++j) {
      const float a = p[2 * j], c = p[2 * j + 1];
      const ushort h0 = __builtin_bit_cast(ushort, (__bf16)a);
      const ushort h1 = __builtin_bit_cast(ushort, (__bf16)c);
      ch[j] = (uint)h0 | ((uint)h1 << 16);
      const float l0 = a - bf2f(h0);
      const float l1 = c - bf2f(h1);
      const ushort g0 = __builtin_bit_cast(ushort, (__bf16)l0);
      const ushort g1 = __builtin_bit_cast(ushort, (__bf16)l1);
      cl[j] = (uint)g0 | ((uint)g1 << 16);
    }
    asm("v_permlane32_swap_b32 %0, %1" : "+v"(ch[0]), "+v"(ch[2]));
    asm("v_permlane32_swap_b32 %0, %1" : "+v"(ch[1]), "+v"(ch[3]));
    asm("v_permlane32_swap_b32 %0, %1" : "+v"(ch[4]), "+v"(ch[6]));
    asm("v_permlane32_swap_b32 %0, %1" : "+v"(ch[5]), "+v"(ch[7]));
    asm("v_permlane32_swap_b32 %0, %1" : "+v"(cl[0]), "+v"(cl[2]));
    asm("v_permlane32_swap_b32 %0, %1" : "+v"(cl[1]), "+v"(cl[3]));
    asm("v_permlane32_swap_b32 %0, %1" : "+v"(cl[4]), "+v"(cl[6]));
    asm("v_permlane32_swap_b32 %0, %1" : "+v"(cl[5]), "+v"(cl[7]));
    short8v paH[2], paL[2];
    {
      uint4v u;
      u = (uint4v){ch[0], ch[1], ch[2], ch[3]};
      paH[0] = __builtin_bit_cast(short8v, u);
      u = (uint4v){ch[4], ch[5], ch[6], ch[7]};
      paH[1] = __builtin_bit_cast(short8v, u);
      u = (uint4v){cl[0], cl[1], cl[2], cl[3]};
      paL[0] = __builtin_bit_cast(short8v, u);
      u = (uint4v){cl[4], cl[5], cl[6], cl[7]};
      paL[1] = __builtin_bit_cast(short8v, u);
    }

    // ---- PV: O[q][d] += P·V ----
#pragma unroll
    for (int dt = 0; dt < 2; ++dt)
#pragma unroll
      for (int ki = 0; ki < 2; ++ki) {
        short8v vbh =
            *(const short8v*)&VT_hi[(dt * 32 + lq) * 40 + ki * 16 + hi5 * 8];
        short8v vbl =
            *(const short8v*)&VT_lo[(dt * 32 + lq) * 40 + ki * 16 + hi5 * 8];
        Oa[dt] = __builtin_amdgcn_mfma_f32_32x32x16_bf16(paH[ki], vbh, Oa[dt], 0, 0, 0);
        Oa[dt] = __builtin_amdgcn_mfma_f32_32x32x16_bf16(paL[ki], vbh, Oa[dt], 0, 0, 0);
        Oa[dt] = __builtin_amdgcn_mfma_f32_32x32x16_bf16(paH[ki], vbl, Oa[dt], 0, 0, 0);
      }
  }

  // ---- epilogue: divide by l, write ao hi/lo planes [B*LQ, 1024] ----
  sc_lds[w][lq] = 1.0f / lrun;
  float4 iv[4];
#pragma unroll
  for (int g = 0; g < 4; ++g)
    iv[g] = *(const float4*)&sc_lds[w][8 * g + 4 * hi5];
#pragma unroll
  for (int dt = 0; dt < 2; ++dt)
#pragma unroll
    for (int r = 0; r < 16; ++r) {
      const int ql = (r & 3) + 8 * (r >> 2) + 4 * hi5;
      const float v = Oa[dt][r] * ((const float*)&iv[r >> 2])[r & 3];
      const size_t idx =
          (size_t)(b * LQ + q0 + ql) * DMODEL + h * 64 + dt * 32 + lq;
      const ushort hbv = f2bf(v);
      AOh[idx] = hbv;
      AOl[idx] = f2bf(v - bf2f(hbv));
    }
}

// ---------------------------------------------------------------------------
// In-place row LayerNorm over 1024 elements. One block per row, 256 threads.
// ---------------------------------------------------------------------------
__global__ __launch_bounds__(256) void ln_kernel(float* __restrict__ io,
                                                 const float* __restrict__ gamma,
                                                 const float* __restrict__ beta) {
  const int row = blockIdx.x;
  const int t = threadIdx.x;
  float* base = io + (size_t)row * DMODEL;
  float4 x = *(const float4*)&base[t << 2];
  float s = x.x + x.y + x.z + x.w;
#pragma unroll
  for (int xm = 1; xm < 64; xm <<= 1) s += __shfl_xor(s, xm, 64);
  __shared__ float part[4];
  __shared__ float smu, svar;
  if ((t & 63) == 0) part[t >> 6] = s;
  __syncthreads();
  if (t == 0) smu = (part[0] + part[1] + part[2] + part[3]) * (1.0f / DMODEL);
  __syncthreads();
  const float mu = smu;
  const float d0 = x.x - mu, d1 = x.y - mu, d2 = x.z - mu, d3 = x.w - mu;
  float s2 = d0 * d0 + d1 * d1 + d2 * d2 + d3 * d3;
#pragma unroll
  for (int xm = 1; xm < 64; xm <<= 1) s2 += __shfl_xor(s2, xm, 64);
  if ((t & 63) == 0) part[t >> 6] = s2;
  __syncthreads();
  if (t == 0) svar = (part[0] + part[1] + part[2] + part[3]) * (1.0f / DMODEL);
  __syncthreads();
  const float inv = rsqrtf(svar + 1e-6f);
  float4 g = *(const float4*)&gamma[t << 2];
  float4 be = *(const float4*)&beta[t << 2];
  float4 o;
  o.x = d0 * inv * g.x + be.x;
  o.y = d1 * inv * g.y + be.y;
  o.z = d2 * inv * g.z + be.z;
  o.w = d3 * inv * g.w + be.w;
  *(float4*)&base[t << 2] = o;
}

extern "C" void kernel_launch(void* const* d_in, const int* in_sizes, int n_in,
                              void* d_out, int out_size, void* d_ws,
                              size_t ws_size, hipStream_t stream) {
  const float* q = (const float*)d_in[0];
  const float* k = (const float*)d_in[1];
  const float* v = (const float*)d_in[2];
  const int* mask = (const int*)d_in[3];
  const float* mean = (const float*)d_in[4];
  const float* stdv = (const float*)d_in[5];
  const float* w_qs = (const float*)d_in[6];
  const float* w_ks = (const float*)d_in[7];
  const float* w_vs = (const float*)d_in[8];
  const float* w_fc = (const float*)d_in[9];
  const float* gamma = (const float*)d_in[10];
  const float* beta = (const float*)d_in[11];
  float* out = (float*)d_out;

  // workspace (ushort), 112 MB total:
  // xinH[3*PL] | xinL[3*PL] | prH[3*PL] | prL[3*PL] | wT_h[4*WL] | wT_l[4*WL]
  ushort* xinH = (ushort*)d_ws;
  ushort* xinL = xinH + 3 * PLANE;
  ushort* prH  = xinL + 3 * PLANE;
  ushort* prL  = prH + 3 * PLANE;
  ushort* wT_h = prL + 3 * PLANE;
  ushort* wT_l = wT_h + 4 * WPLANE;
  ushort* aoH = xinH;  // alias: xin planes dead after projections
  ushort* aoL = xinL;

  dim3 blk(256);
  const int n4 = MROWS * DMODEL / 4;

  conv_wT<<<dim3(16, 16, 4), blk, 0, stream>>>(w_qs, w_ks, w_vs, w_fc, wT_h, wT_l);
  conv_x3<<<dim3(512, 1, 3), blk, 0, stream>>>(q, k, v, xinH, xinL, n4);

  gemm_mfma<3><<<dim3(8, 32, 3), blk, 0, stream>>>(
      xinH, xinL, wT_h, wT_l, prH, prL, nullptr, nullptr);

  attn_mfma<<<dim3(16, 16, 2), blk, 0, stream>>>(
      prH, prL, prH + PLANE, prL + PLANE, prH + 2 * PLANE, prL + 2 * PLANE,
      mask, mean, stdv, aoH, aoL);

  gemm_mfma<1><<<dim3(8, 32), blk, 0, stream>>>(
      aoH, aoL, wT_h + 3 * WPLANE, wT_l + 3 * WPLANE, nullptr, nullptr, out, q);
  ln_kernel<<<MROWS, blk, 0, stream>>>(out, gamma, beta);
}